// Round 7
// baseline (219.403 us; speedup 1.0000x reference)
//
#include <hip/hip_runtime.h>
#include <hip/hip_bf16.h>
#include <math.h>
#include <float.h>

typedef __attribute__((ext_vector_type(8))) short short8;
typedef __attribute__((ext_vector_type(8))) ushort ushort8;
typedef __attribute__((ext_vector_type(4))) float f32x4;

namespace {

constexpr int B = 256;
constexpr int M = 65536;
constexpr int D = 1024;
constexpr float DECAY_EPS = 1e-8f;
constexpr float DECAY_RATE = 0.999f;

constexpr int BN = 32;          // keys per GEMM block
constexpr int KSTEPS = D / 32;  // 32 MFMA-K steps

constexpr int CHUNKS = 8;           // top-k chunks per row
constexpr int CHUNK = M / CHUNKS;   // 8192
constexpr int NCAND = CHUNKS * 8;   // 64 candidates per row

__device__ inline ushort f2bf(float f) {
  union { float f; unsigned u; } v; v.f = f;
  unsigned r = v.u + 0x7fffu + ((v.u >> 16) & 1u);  // RNE
  return (ushort)(r >> 16);
}

__device__ inline short bfs(float f) {
  __hip_bfloat16 h = __float2bfloat16(f);  // hardware RNE (v_cvt_pk fusable)
  return *reinterpret_cast<const short*>(&h);
}

__device__ inline short8 pack8(float4 u, float4 v) {
  short8 r;
  r[0] = bfs(u.x); r[1] = bfs(u.y); r[2] = bfs(u.z); r[3] = bfs(u.w);
  r[4] = bfs(v.x); r[5] = bfs(v.y); r[6] = bfs(v.z); r[7] = bfs(v.w);
  return r;
}

__device__ inline float dot4(float4 a) {
  return a.x * a.x + a.y * a.y + a.z * a.z + a.w * a.w;
}

// ---------------------------------------------------------------------------
// Kernel 1: normalize queries, emit bf16 in MFMA A-fragment order:
// qnf[(kt*16 + mt)*512 + l*8 + j] = qn[mt*16 + (l&15)][kt*32 + (l>>4)*8 + j]
// ---------------------------------------------------------------------------
__global__ void prep_q_kernel(const float* __restrict__ q, ushort* __restrict__ qnf) {
  const int r = blockIdx.x;
  const int t = threadIdx.x;  // 256 threads x float4
  float4 v = reinterpret_cast<const float4*>(q + (size_t)r * D)[t];
  float ss = v.x * v.x + v.y * v.y + v.z * v.z + v.w * v.w;
#pragma unroll
  for (int off = 32; off; off >>= 1) ss += __shfl_down(ss, off, 64);
  __shared__ float red[4];
  if ((t & 63) == 0) red[t >> 6] = ss;
  __syncthreads();
  const float inv = 1.0f / fmaxf(sqrtf(red[0] + red[1] + red[2] + red[3]), DECAY_EPS);
  ushort4 o;
  o.x = f2bf(v.x * inv); o.y = f2bf(v.y * inv);
  o.z = f2bf(v.z * inv); o.w = f2bf(v.w * inv);
  const int k0 = t * 4;
  const int kt = k0 >> 5;
  const int lane_slot = (r & 15) + 16 * ((k0 & 31) >> 3);
  const int j0 = k0 & 7;  // 0 or 4
  *reinterpret_cast<ushort4*>(qnf + (size_t)(kt * 16 + (r >> 4)) * 512 + lane_slot * 8 + j0) = o;
}

// ---------------------------------------------------------------------------
// Kernel 2: bf16-MFMA scores -> bf16 score matrix [B][M].
// BARRIER-FREE, LDS-FREE streaming GEMM. BM=256 x BN=32 per block, 256 thr
// (4 waves). Wave w owns m-frags w*4..w*4+3; both n-frags. B-fragments are
// loaded DIRECTLY from keys in fragment layout (lane (q,h) reads 2x float4
// from row jb+nf*16+q), converted in-register; double-buffered (s+1 issued
// while s computes) with no barrier ever draining them. Key norms are
// lane-local; cscale computed in-register.
// ---------------------------------------------------------------------------
__global__ __launch_bounds__(256) void score_gemm_kernel(
    const ushort* __restrict__ qnf, const float* __restrict__ keys,
    const float* __restrict__ importance, const int* __restrict__ atimes,
    const int* __restrict__ acnts, const int* __restrict__ ctime,
    ushort* __restrict__ scores) {
  const int t = threadIdx.x;
  const int lane = t & 63;
  const int w = t >> 6;      // wave 0..3
  const int h = lane >> 4;   // 0..3 (k-slice)
  const int q = lane & 15;   // 0..15 (key col within frag)
  const int jb = blockIdx.x * BN;

  const float* kb0 = keys + (size_t)(jb + q) * D + h * 8;
  const float* kb1 = keys + (size_t)(jb + 16 + q) * D + h * 8;
  const short8* ap = reinterpret_cast<const short8*>(qnf) + (size_t)(w * 4) * 64 + lane;

  f32x4 acc[4][2];
#pragma unroll
  for (int f = 0; f < 4; ++f)
#pragma unroll
    for (int n = 0; n < 2; ++n) acc[f][n] = (f32x4)(0.0f);

  float kn0 = 0.0f, kn1 = 0.0f;  // lane-local norm partials (rows jb+q, jb+16+q)

  short8 aA[4], aB[4];
  float4 bA[4], bB[4];

  auto LA = [&](short8* aa, int s) {
#pragma unroll
    for (int f = 0; f < 4; ++f) aa[f] = ap[(size_t)(s * 16 + f) * 64];
  };
  auto LB = [&](float4* bb, int s) {
    bb[0] = *reinterpret_cast<const float4*>(kb0 + s * 32);
    bb[1] = *reinterpret_cast<const float4*>(kb0 + s * 32 + 4);
    bb[2] = *reinterpret_cast<const float4*>(kb1 + s * 32);
    bb[3] = *reinterpret_cast<const float4*>(kb1 + s * 32 + 4);
  };
  auto CMP = [&](short8* aa, float4* bb) {
    kn0 += dot4(bb[0]) + dot4(bb[1]);
    kn1 += dot4(bb[2]) + dot4(bb[3]);
    const short8 b0 = pack8(bb[0], bb[1]);
    const short8 b1 = pack8(bb[2], bb[3]);
#pragma unroll
    for (int f = 0; f < 4; ++f) {
      acc[f][0] = __builtin_amdgcn_mfma_f32_16x16x32_bf16(aa[f], b0, acc[f][0], 0, 0, 0);
      acc[f][1] = __builtin_amdgcn_mfma_f32_16x16x32_bf16(aa[f], b1, acc[f][1], 0, 0, 0);
    }
  };

  LA(aA, 0); LB(bA, 0);
  for (int it = 0; it < KSTEPS / 2; ++it) {
    LA(aB, 2 * it + 1); LB(bB, 2 * it + 1);   // issue s+1 (never drained)
    CMP(aA, bA);                              // compute s
    if (it < KSTEPS / 2 - 1) { LA(aA, 2 * it + 2); LB(bA, 2 * it + 2); }
    CMP(aB, bB);
  }

  // full norms: sum over the 4 h-slices (lanes differing in bits 4-5)
  kn0 += __shfl_xor(kn0, 16, 64); kn0 += __shfl_xor(kn0, 32, 64);
  kn1 += __shfl_xor(kn1, 16, 64); kn1 += __shfl_xor(kn1, 32, 64);

  const int ct = ctime[0];
  float cs[2];
  {
    const int j = jb + q;
    const float mult = powf(DECAY_RATE, (float)(ct - atimes[j])) * importance[j] *
                       log1pf((float)acnts[j]);
    cs[0] = mult / fmaxf(sqrtf(kn0), DECAY_EPS);
  }
  {
    const int j = jb + 16 + q;
    const float mult = powf(DECAY_RATE, (float)(ct - atimes[j])) * importance[j] *
                       log1pf((float)acnts[j]);
    cs[1] = mult / fmaxf(sqrtf(kn1), DECAY_EPS);
  }

  // epilogue: C/D col = q, row = h*4 + rr within frag; pack col pairs, u32 store
#pragma unroll
  for (int f = 0; f < 4; ++f) {
    const int row0 = (w * 4 + f) * 16 + (h << 2);
#pragma unroll
    for (int nf = 0; nf < 2; ++nf) {
#pragma unroll
      for (int rr = 0; rr < 4; ++rr) {
        const float v = acc[f][nf][rr] * cs[nf];
        const float vn = __shfl_xor(v, 1, 64);
        if (!(q & 1)) {
          const uint pk = (uint)f2bf(v) | ((uint)f2bf(vn) << 16);
          *reinterpret_cast<uint*>(
              scores + (size_t)(row0 + rr) * M + jb + nf * 16 + q) = pk;
        }
      }
    }
  }
}

// ---------------------------------------------------------------------------
// Kernel 3 (stage A): per (row, chunk) top-8 indices over bf16 scores.
// Packed u32 = (monotone_key16 << 16) | local_idx16; integer compares.
// ---------------------------------------------------------------------------
__global__ __launch_bounds__(256) void topk_partial_kernel(
    const ushort* __restrict__ scores, int* __restrict__ cand_i) {
  const int b = blockIdx.y;
  const int c = blockIdx.x;
  const int t = threadIdx.x;
  const int lane = t & 63, w = t >> 6;
  const ushort8* base8 =
      reinterpret_cast<const ushort8*>(scores + (size_t)b * M + (size_t)c * CHUNK);

  uint s8[8];
#pragma unroll
  for (int i = 0; i < 8; ++i) s8[i] = 0;

  auto ins = [&](uint x) {
    if (x > s8[0]) {
#pragma unroll
      for (int i = 0; i < 8; ++i) {
        const bool up = (i < 7) && (x > s8[i + 1]);
        const uint keep = (x > s8[i]) ? x : s8[i];
        s8[i] = up ? s8[i + 1] : keep;
      }
    }
  };

  const uint jbase = (uint)c * CHUNK;
#pragma unroll
  for (int it = 0; it < CHUNK / (256 * 8); ++it) {  // 4 iters
    const int slot = it * 256 + t;
    const ushort8 v = base8[slot];
    const uint j0 = jbase + (uint)slot * 8;
#pragma unroll
    for (int e = 0; e < 8; ++e) {
      const ushort s = (ushort)v[e];
      const ushort key = (s & 0x8000) ? (ushort)~s : (ushort)(s | 0x8000);
      ins(((uint)key << 16) | ((j0 + e) & 0xFFFFu));
    }
  }

  __shared__ uint ls[2048];
#pragma unroll
  for (int i = 0; i < 8; ++i) ls[t * 8 + i] = s8[i];
  __syncthreads();

  __shared__ uint rs4[4];
  __shared__ int rp4[4];
  for (int r = 0; r < 8; ++r) {
    uint ms = 0;
    int mp = 0;
#pragma unroll
    for (int i = 0; i < 8; ++i) {
      const uint v = ls[i * 256 + t];
      if (v > ms) { ms = v; mp = i * 256 + t; }
    }
#pragma unroll
    for (int off = 32; off; off >>= 1) {
      const uint ov = __shfl_xor(ms, off, 64);
      const int op = __shfl_xor(mp, off, 64);
      if (ov > ms) { ms = ov; mp = op; }
    }
    if (lane == 0) { rs4[w] = ms; rp4[w] = mp; }
    __syncthreads();
    if (t == 0) {
      uint bs = 0;
      int bp = 0;
#pragma unroll
      for (int i = 0; i < 4; ++i)
        if (rs4[i] > bs) { bs = rs4[i]; bp = rp4[i]; }
      cand_i[((size_t)b * CHUNKS + c) * 8 + r] = (int)(ls[bp] & 0xFFFFu);
      ls[bp] = 0;
    }
    __syncthreads();
  }
}

// ---------------------------------------------------------------------------
// Kernel 4 (stage B): exact fp32 rescore of 64 candidates, top-8, softmax,
// weighted value gather. One block (512 thr = 8 waves) per row.
// ---------------------------------------------------------------------------
__global__ __launch_bounds__(512) void rescore_kernel(
    const int* __restrict__ cand_i, const float* __restrict__ query,
    const float* __restrict__ keys, const float* __restrict__ values,
    const float* __restrict__ importance, const int* __restrict__ atimes,
    const int* __restrict__ acnts, const int* __restrict__ ctime,
    float* __restrict__ outc, float* __restrict__ conf) {
  const int b = blockIdx.x;
  const int t = threadIdx.x;
  const int lane = t & 63, w = t >> 6;

  const float4* qv4 = reinterpret_cast<const float4*>(query + (size_t)b * D + lane * 16);
  float4 q0 = qv4[0], q1 = qv4[1], q2 = qv4[2], q3 = qv4[3];
  float ssq = dot4(q0) + dot4(q1) + dot4(q2) + dot4(q3);
#pragma unroll
  for (int off = 32; off; off >>= 1) ssq += __shfl_xor(ssq, off, 64);
  const float qdn = fmaxf(sqrtf(ssq), DECAY_EPS);
  const int ct = ctime[0];

  __shared__ float sc[NCAND];
  __shared__ int sidx[NCAND];

  for (int u = 0; u < 8; ++u) {
    const int c = w * 8 + u;
    const int j = cand_i[(size_t)b * NCAND + c];
    const float4* kv4 = reinterpret_cast<const float4*>(keys + (size_t)j * D + lane * 16);
    const float4 k0 = kv4[0], k1 = kv4[1], k2 = kv4[2], k3 = kv4[3];
    float dd = q0.x * k0.x + q0.y * k0.y + q0.z * k0.z + q0.w * k0.w
             + q1.x * k1.x + q1.y * k1.y + q1.z * k1.z + q1.w * k1.w
             + q2.x * k2.x + q2.y * k2.y + q2.z * k2.z + q2.w * k2.w
             + q3.x * k3.x + q3.y * k3.y + q3.z * k3.z + q3.w * k3.w;
    float nn = dot4(k0) + dot4(k1) + dot4(k2) + dot4(k3);
#pragma unroll
    for (int off = 32; off; off >>= 1) {
      dd += __shfl_xor(dd, off, 64);
      nn += __shfl_xor(nn, off, 64);
    }
    if (lane == 0) {
      const float dtv = (float)(ct - atimes[j]);
      const float mult = powf(DECAY_RATE, dtv) * importance[j] * log1pf((float)acnts[j]);
      sc[c] = dd / (qdn * fmaxf(sqrtf(nn), DECAY_EPS)) * mult;
      sidx[c] = j;
    }
  }
  __syncthreads();

  __shared__ float w8s[8];
  __shared__ int g8[8];
  __shared__ float confv;
  __shared__ float tls[8];
  __shared__ int tli[8];
  if (w == 0) {
    float myv = sc[lane];
    for (int r = 0; r < 8; ++r) {
      float m = myv;
      int mi = lane;
#pragma unroll
      for (int off = 32; off; off >>= 1) {
        const float ov = __shfl_xor(m, off, 64);
        const int oi = __shfl_xor(mi, off, 64);
        if (ov > m || (ov == m && oi < mi)) { m = ov; mi = oi; }
      }
      if (lane == 0) { tls[r] = m; tli[r] = mi; }
      if (lane == mi) myv = -FLT_MAX;
    }
    if (lane == 0) {
      const float mx = tls[0];
      float e[8];
      float z = 0.0f;
#pragma unroll
      for (int r = 0; r < 8; ++r) { e[r] = expf(tls[r] - mx); z += e[r]; }
      const float invz = 1.0f / z;
#pragma unroll
      for (int r = 0; r < 8; ++r) { w8s[r] = e[r] * invz; g8[r] = sidx[tli[r]]; }
      confv = w8s[0];
    }
  }
  __syncthreads();

  float2 acc = make_float2(0.0f, 0.0f);
#pragma unroll
  for (int k = 0; k < 8; ++k) {
    const float wk = w8s[k];
    const float2 v = *reinterpret_cast<const float2*>(values + (size_t)g8[k] * D + 2 * t);
    acc.x = fmaf(wk, v.x, acc.x);
    acc.y = fmaf(wk, v.y, acc.y);
  }
  *reinterpret_cast<float2*>(outc + (size_t)b * D + 2 * t) = acc;
  if (t == 0) conf[b] = confv;
}

}  // namespace

extern "C" void kernel_launch(void* const* d_in, const int* in_sizes, int n_in,
                              void* d_out, int out_size, void* d_ws, size_t ws_size,
                              hipStream_t stream) {
  const float* query = (const float*)d_in[0];
  const float* keys = (const float*)d_in[1];
  const float* values = (const float*)d_in[2];
  const float* importance = (const float*)d_in[3];
  const int* atimes = (const int*)d_in[4];
  const int* acnts = (const int*)d_in[5];
  const int* ctime = (const int*)d_in[6];

  float* out = (float*)d_out;  // combined [B*D] then confidence [B]
  ushort* qnf = (ushort*)d_ws;                 // 512 KB
  ushort* scores = qnf + (size_t)B * D;        // 32 MB bf16
  int* cand = (int*)(scores + (size_t)B * M);  // 64 KB

  prep_q_kernel<<<B, 256, 0, stream>>>(query, qnf);
  score_gemm_kernel<<<M / BN, 256, 0, stream>>>(qnf, keys, importance, atimes,
                                                acnts, ctime, scores);
  dim3 gA(CHUNKS, B);
  topk_partial_kernel<<<gA, 256, 0, stream>>>(scores, cand);
  rescore_kernel<<<B, 512, 0, stream>>>(cand, query, keys, values, importance,
                                        atimes, acnts, ctime, out, out + (size_t)B * D);
}